// Round 13
// baseline (109.622 us; speedup 1.0000x reference)
//
#include <hip/hip_runtime.h>
#include <math.h>

#define NB 65536
#define EV 131072
#define NE (2*EV)
#define DM 128
#define BM 128
#define NT 10
#define THREADS 512

typedef float f32x4 __attribute__((ext_vector_type(4)));
typedef int   i32x4 __attribute__((ext_vector_type(4)));
typedef unsigned long long u64;

// ---- fast transcendentals (HW ops) ----
__device__ __forceinline__ float fcos_rev(float rev) {
    float r; asm("v_cos_f32 %0, %1" : "=v"(r) : "v"(rev)); return r;
}
__device__ __forceinline__ float fexp2(float x) {
    float r; asm("v_exp_f32 %0, %1" : "=v"(r) : "v"(x)); return r;
}
__device__ __forceinline__ float frcp(float x) {
    float r; asm("v_rcp_f32 %0, %1" : "=v"(r) : "v"(x)); return r;
}
__device__ __forceinline__ float fast_cos(float arg) {   // |arg| up to ~1e6
    double rv = (double)arg * 0.15915494309189535;
    rv -= floor(rv);
    return fcos_rev((float)rv);
}
__device__ __forceinline__ float fsigmoid(float x) {
    x = fminf(fmaxf(x, -30.f), 30.f);
    float e = fexp2(-1.44269504088896f * x);
    return frcp(1.f + e);
}
__device__ __forceinline__ float ftanh_(float x) {
    x = fminf(fmaxf(x, -15.f), 15.f);
    float e = fexp2(-2.88539008177793f * x);
    return (1.f - e) * frcp(1.f + e);
}

// ---- fp8 e4m3 packing ----
#if defined(__has_builtin) && __has_builtin(__builtin_amdgcn_cvt_pk_fp8_f32)
__device__ __forceinline__ unsigned pack4_fp8(float f0, float f1, float f2, float f3) {
    int v = __builtin_amdgcn_cvt_pk_fp8_f32(f0, f1, 0, false);
    v = __builtin_amdgcn_cvt_pk_fp8_f32(f2, f3, v, true);
    return (unsigned)v;
}
#else
__device__ __forceinline__ unsigned enc1_fp8(float x) {
    unsigned u = __float_as_uint(x);
    unsigned s = (u >> 24) & 0x80u;
    float a = fabsf(x);
    if (!(a >= 0.001953125f)) return s;
    if (a > 448.f) a = 448.f;
    int e; float mf = frexpf(a, &e);
    int E = e + 6, mant;
    if (E <= 0) {
        mant = (int)(a * 512.f + 0.5f);
        if (mant > 7) return s | 0x08u;
        return s | (unsigned)mant;
    }
    mant = (int)((mf * 2.f - 1.f) * 8.f + 0.5f);
    if (mant == 8) { mant = 0; ++E; }
    if (E > 15) { E = 15; mant = 6; }
    if (E == 15 && mant == 7) mant = 6;
    return s | (unsigned)(E << 3) | (unsigned)mant;
}
__device__ __forceinline__ unsigned pack4_fp8(float f0, float f1, float f2, float f3) {
    return enc1_fp8(f0) | (enc1_fp8(f1) << 8) | (enc1_fp8(f2) << 16) | (enc1_fp8(f3) << 24);
}
#endif

// ---------------- fused prep: event argmax scan + W' build ----------------
// wp8 gll-linear: L = col*64 + slot*8 within tile t; slot holds granule
// g = slot ^ ((col>>1)&3); value = W'[col][t*64 + g*8 + j] * 16 (fp8).
__global__ void prep_k(const int* __restrict__ src_s, const int* __restrict__ t_s,
                       const int* __restrict__ dst_d, const int* __restrict__ t_d,
                       u64* __restrict__ keyarr, u64* __restrict__ lukey,
                       const float* __restrict__ W_ih, const float* __restrict__ W_hh,
                       const float* __restrict__ b_ih, const float* __restrict__ b_hh,
                       unsigned char* __restrict__ wp8, float* __restrict__ bp) {
    int bid = blockIdx.x;
    if (bid < NE / 256) {
        int e = bid * 256 + threadIdx.x;
        int g, t;
        if (e < EV) { g = src_s[e];      t = t_s[e]; }
        else        { g = dst_d[e - EV]; t = t_d[e - EV]; }
        u64 key = ((u64)(unsigned)t << 18) + (u64)(unsigned)e + 1ull;
        atomicMax(&keyarr[g], key);
        u64 lk = ((u64)(unsigned)(e + 1) << 20) | (u64)(unsigned)t;   // t < 2^20
        atomicMax(&lukey[g], lk);
        return;
    }
    int idx = (bid - NE / 256) * 256 + threadIdx.x;   // [0, 40960) u64 granules
    int t = idx >> 12, r = idx & 4095;
    int col = r >> 3, slot = r & 7;
    int g = slot ^ ((col >> 1) & 3);
    int k0 = t * 64 + g * 8;
    int d = col >> 2, gate = col & 3;
    float f[8];
    #pragma unroll
    for (int j = 0; j < 8; ++j) {
        int c = k0 + j;
        float v = 0.f;
        if (c < 512) {
            int row = (gate == 0) ? d : (gate == 1) ? 128 + d : (gate == 2) ? 256 + d : -1;
            if (row >= 0) v = W_ih[(size_t)row * 512 + c];
        } else {
            int ch = c - 512;
            int row = (gate == 0) ? d : (gate == 1) ? 128 + d : (gate == 3) ? 256 + d : -1;
            if (row >= 0) v = W_hh[(size_t)row * 128 + ch];
        }
        f[j] = v * 16.f;
    }
    unsigned lo = pack4_fp8(f[0], f[1], f[2], f[3]);
    unsigned hi = pack4_fp8(f[4], f[5], f[6], f[7]);
    *(u64*)(wp8 + (size_t)idx * 8) = (u64)lo | ((u64)hi << 32);
    if (k0 == 0) {   // exactly once per col (t==0, g==0)
        float bv = (gate == 0) ? b_ih[d] + b_hh[d]
                 : (gate == 1) ? b_ih[128 + d] + b_hh[128 + d]
                 : (gate == 2) ? b_ih[256 + d] : b_hh[256 + d];
        bp[col] = bv;
    }
}

// ---------------- 8-phase fused fp8-MFMA GEMM + GRU ----------------
// 128x512 tile, 8 waves (2M x 4N, wave 64x128), BK=64 x 10 tiles, triple-buffered,
// staging 2 tiles ahead, 4 phases/tile x {12 ds_read | stage -> bar -> lgkm(0) ->
// setprio 16 MFMA -> bar}, counted vmcnt at tile end only.
__global__ __launch_bounds__(THREADS, 2) void gemm_gru_k(
    const float* __restrict__ memory, const int* __restrict__ last_update,
    const int* __restrict__ src_s, const int* __restrict__ dst_s,
    const int* __restrict__ t_s, const float* __restrict__ raw_s,
    const int* __restrict__ src_d, const int* __restrict__ dst_d,
    const int* __restrict__ t_d, const float* __restrict__ raw_d,
    const float* __restrict__ w_time, const float* __restrict__ b_time,
    const unsigned char* __restrict__ wp8, const float* __restrict__ bp,
    const u64* __restrict__ keyarr, const u64* __restrict__ lukey,
    float* __restrict__ out_mem, float* __restrict__ out_lu)
{
    // sA 3x[128][64B] @0 (24K) | sB 3x[512][64B] @24576 (96K) | sW @122880 | sBt @123392
    // epilogue: per-wave [16][132] f32 @ wid*8448 (overlays after syncthreads)
    __shared__ __align__(16) char smem[123904];
    unsigned char* sA = (unsigned char*)smem;
    unsigned char* sB = (unsigned char*)(smem + 24576);
    float* sW  = (float*)(smem + 122880);
    float* sBt = (float*)(smem + 123392);

    const int tid = threadIdx.x;
    const int m0  = blockIdx.x * BM;
    const int ln  = tid & 63, wid = tid >> 6;
    const int wr  = wid >> 2, wc = wid & 3;          // 2M x 4N
    const int l2  = ln >> 4, rl = ln & 15;

    if (tid < DM) { sW[tid] = w_time[tid]; sBt[tid] = b_time[tid]; }

    // ---- per-thread decode (4 threads per row) ----
    const int ar = tid >> 2, kc = tid & 3;           // row (0..127), 16-float chunk (0..3)
    const int m  = m0 + ar;
    const u64 kk = keyarr[m];
    const int rv = (kk != 0ull);
    int a_ = 0, b_ = 0, t_ = 0;
    const float* pR = raw_s;
    if (kk) {
        int e = (int)((kk - 1ull) & (u64)(NE - 1));
        if (e < EV) { a_ = src_s[e]; b_ = dst_s[e]; t_ = t_s[e]; pR = raw_s + (size_t)e * DM; }
        else { int e2 = e - EV; a_ = dst_d[e2]; b_ = src_d[e2]; t_ = t_d[e2]; pR = raw_d + (size_t)e2 * DM; }
    }
    const float rt = rv ? (float)(t_ - last_update[a_]) : 0.f;
    const float* pA = memory + (size_t)a_ * DM;
    const float* pB = memory + (size_t)b_ * DM;
    const float* pH = memory + (size_t)m  * DM;      // n_id = arange

    float4 pv[4];                                    // A prefetch regs (16 floats)
    auto PREF_A = [&](int t) {                       // issue tile t's A window
        const float* base; int off;
        if (t < 2)      { base = pA; off = (t & 1) * 64; }
        else if (t < 4) { base = pB; off = (t & 1) * 64; }
        else if (t < 6) { base = pR; off = (t & 1) * 64; }
        else            { base = pH; off = (t - 8) * 64; }   // t>=8 (6,7 never called)
        const float* p = base + off + kc * 16;
        pv[0] = *(const float4*)(p);
        pv[1] = *(const float4*)(p + 4);
        pv[2] = *(const float4*)(p + 8);
        pv[3] = *(const float4*)(p + 12);
    };
    auto GLL_B = [&](int t) {                        // 4 gll x16B, linear both sides
        const unsigned char* src = wp8 + (size_t)t * 32768 + (size_t)tid * 16;
        unsigned char* dst = sB + (size_t)(t % 3) * 32768 + (size_t)tid * 16;
        #pragma unroll
        for (int i = 0; i < 4; ++i)
            __builtin_amdgcn_global_load_lds(
                (const __attribute__((address_space(1))) void*)(src + i * 8192),
                (__attribute__((address_space(3))) void*)(dst + i * 8192), 16, 0, 0);
    };
    auto WRITE_A = [&](int t) {                      // cvt x16 + pack + swizzled b128
        unsigned p0, p1, p2, p3;
        if (t >= 6 && t < 8) {
            int coff = (t & 1) * 64 + kc * 16;
            float c[16];
            #pragma unroll
            for (int j = 0; j < 16; ++j)
                c[j] = fast_cos(__fadd_rn(__fmul_rn(rt, sW[coff + j]), sBt[coff + j]));
            p0 = pack4_fp8(c[0], c[1], c[2], c[3]);
            p1 = pack4_fp8(c[4], c[5], c[6], c[7]);
            p2 = pack4_fp8(c[8], c[9], c[10], c[11]);
            p3 = pack4_fp8(c[12], c[13], c[14], c[15]);
        } else {
            p0 = pack4_fp8(pv[0].x, pv[0].y, pv[0].z, pv[0].w);
            p1 = pack4_fp8(pv[1].x, pv[1].y, pv[1].z, pv[1].w);
            p2 = pack4_fp8(pv[2].x, pv[2].y, pv[2].z, pv[2].w);
            p3 = pack4_fp8(pv[3].x, pv[3].y, pv[3].z, pv[3].w);
        }
        if (t < 8 && !rv) { p0 = p1 = p2 = p3 = 0u; }
        int swz = (ar >> 1) & 3;
        i32x4 v = (swz & 1) ? (i32x4){(int)p2, (int)p3, (int)p0, (int)p1}
                            : (i32x4){(int)p0, (int)p1, (int)p2, (int)p3};
        *(i32x4*)(sA + (size_t)(t % 3) * 8192 + ar * 64 + (((2 * kc) ^ (swz & 2)) << 3)) = v;
    };

    f32x4 acc[4][8];
    #pragma unroll
    for (int mf = 0; mf < 4; ++mf)
        #pragma unroll
        for (int nf = 0; nf < 8; ++nf)
            acc[mf][nf] = (f32x4){0.f, 0.f, 0.f, 0.f};

    // ---- prologue: stage tiles 0,1 fully; pref A(2) in flight ----
    PREF_A(0);
    WRITE_A(0);                 // reg-dep waits pv
    PREF_A(1);
    WRITE_A(1);
    GLL_B(0);
    GLL_B(1);
    PREF_A(2);
    asm volatile("s_waitcnt vmcnt(8) lgkmcnt(0)" ::: "memory");   // gll(0)+sA writes done
    __builtin_amdgcn_sched_barrier(0);
    __builtin_amdgcn_s_barrier();

    // ---- 8-phase K-loop: 10 tiles x 4 phases ----
    #pragma unroll
    for (int t = 0; t < NT; ++t) {
        #pragma unroll
        for (int ph = 0; ph < 4; ++ph) {
            const int mh = ph >> 1, nh = ph & 1;

            // fragment reads for THIS phase (latency spans the barrier)
            long afr[2][2], bfr[4][2];
            {
                const unsigned char* aB = sA + (size_t)(t % 3) * 8192;
                #pragma unroll
                for (int mi = 0; mi < 2; ++mi) {
                    int r = wr * 64 + (mh * 2 + mi) * 16 + rl;
                    int so = ((l2 ^ ((r >> 1) & 3)) << 3);
                    afr[mi][0] = *(const long*)(aB + r * 64 + so);
                    afr[mi][1] = *(const long*)(aB + r * 64 + so + 32);
                }
                const unsigned char* bB = sB + (size_t)(t % 3) * 32768;
                #pragma unroll
                for (int ni = 0; ni < 4; ++ni) {
                    int c = wc * 128 + (nh * 4 + ni) * 16 + rl;
                    int so = ((l2 ^ ((c >> 1) & 3)) << 3);
                    bfr[ni][0] = *(const long*)(bB + c * 64 + so);
                    bfr[ni][1] = *(const long*)(bB + c * 64 + so + 32);
                }
            }
            // staging: phase 0 = A-write(t+2) + B-gll(t+2); phase 1 = A-pref(t+3)
            if (ph == 0 && t + 2 < NT) { WRITE_A(t + 2); GLL_B(t + 2); }
            if (ph == 1 && t + 3 < NT && !(t + 3 == 6 || t + 3 == 7)) PREF_A(t + 3);

            __builtin_amdgcn_sched_barrier(0);
            __builtin_amdgcn_s_barrier();
            asm volatile("s_waitcnt lgkmcnt(0)" ::: "memory");
            __builtin_amdgcn_sched_barrier(0);

            __builtin_amdgcn_s_setprio(1);
            #pragma unroll
            for (int ks = 0; ks < 2; ++ks)
                #pragma unroll
                for (int mi = 0; mi < 2; ++mi)
                    #pragma unroll
                    for (int ni = 0; ni < 4; ++ni)
                        acc[mh * 2 + mi][nh * 4 + ni] =
                            __builtin_amdgcn_mfma_f32_16x16x32_fp8_fp8(
                                afr[mi][ks], bfr[ni][ks],
                                acc[mh * 2 + mi][nh * 4 + ni], 0, 0, 0);
            __builtin_amdgcn_s_setprio(0);
            __builtin_amdgcn_sched_barrier(0);

            if (ph == 3) {
                if (t < NT - 1) {   // tile-end: counted drain, keep t+2 staging in flight
                    if (t == 3 || t == 4 || t == 7)
                        asm volatile("s_waitcnt vmcnt(4) lgkmcnt(0)" ::: "memory");
                    else if (t == 8)
                        asm volatile("s_waitcnt vmcnt(0) lgkmcnt(0)" ::: "memory");
                    else
                        asm volatile("s_waitcnt vmcnt(8) lgkmcnt(0)" ::: "memory");
                    __builtin_amdgcn_sched_barrier(0);
                    __builtin_amdgcn_s_barrier();
                }
            } else {
                __builtin_amdgcn_s_barrier();
            }
        }
    }

    // ---- new_last_update (folded) ----
    if (tid < BM) {
        u64 lk = lukey[m0 + tid];
        out_lu[m0 + tid] = lk ? (float)(unsigned)(lk & 0xFFFFFull)
                              : (float)last_update[m0 + tid];
    }
    __syncthreads();    // all frag reads done; per-wave scratch overlays sA/sB

    // ---- epilogue: per-wave LDS transpose, fused GRU ----
    float* ep = (float*)(smem + wid * 8448);          // [16][132] f32
    const int row16 = ln >> 2, dq = ln & 3;
    const int d8 = wc * 32 + dq * 8;
    const float dsc = 0.0625f;                        // 1/16 (W scale)

    #pragma unroll
    for (int mf = 0; mf < 4; ++mf) {
        #pragma unroll
        for (int nf = 0; nf < 8; ++nf)
            #pragma unroll
            for (int reg = 0; reg < 4; ++reg)
                ep[(l2 * 4 + reg) * 132 + nf * 16 + rl] = acc[mf][nf][reg] * dsc;
        asm volatile("s_waitcnt lgkmcnt(0)" ::: "memory");   // wave-local write->read

        const int gm = m0 + wr * 64 + mf * 16 + row16;
        #pragma unroll
        for (int q = 0; q < 8; ++q) {
            int q2 = (q + dq) & 7;                    // rotation via addresses only
            f32x4 g  = *(const f32x4*)(ep + row16 * 132 + dq * 32 + q2 * 4);
            f32x4 bb = *(const f32x4*)(bp + (size_t)(d8 + q2) * 4);
            float rg = fsigmoid(g.x + bb.x);
            float zg = fsigmoid(g.y + bb.y);
            float ng = ftanh_(g.z + bb.z + rg * (g.w + bb.w));
            float hh = memory[(size_t)gm * DM + d8 + q2];
            out_mem[(size_t)gm * DM + d8 + q2] = (1.f - zg) * ng + zg * hh;
        }
        if (mf < 3) asm volatile("s_waitcnt lgkmcnt(0)" ::: "memory");
    }
}

extern "C" void kernel_launch(void* const* d_in, const int* in_sizes, int n_in,
                              void* d_out, int out_size, void* d_ws, size_t ws_size,
                              hipStream_t stream) {
    const float* memory      = (const float*)d_in[0];
    const int*   last_update = (const int*)d_in[1];
    const int*   src_s       = (const int*)d_in[3];
    const int*   dst_s       = (const int*)d_in[4];
    const int*   t_s         = (const int*)d_in[5];
    const float* raw_s       = (const float*)d_in[6];
    const int*   src_d       = (const int*)d_in[7];
    const int*   dst_d       = (const int*)d_in[8];
    const int*   t_d         = (const int*)d_in[9];
    const float* raw_d       = (const float*)d_in[10];
    const float* w_time      = (const float*)d_in[11];
    const float* b_time      = (const float*)d_in[12];
    const float* W_ih        = (const float*)d_in[13];
    const float* W_hh        = (const float*)d_in[14];
    const float* b_ih        = (const float*)d_in[15];
    const float* b_hh        = (const float*)d_in[16];

    // workspace
    char* ws = (char*)d_ws;
    u64* keyarr = (u64*)ws;                                 // 512KB
    u64* lukey  = (u64*)(ws + 524288);                      // 512KB
    unsigned char* wp8 = (unsigned char*)(ws + 1048576);    // 320KB (10 tiles x 32KB)
    float* bp = (float*)(ws + 1376256);                     // 2KB

    hipMemsetAsync(d_ws, 0, 1048576, stream);               // keyarr + lukey

    prep_k<<<NE / 256 + 160, 256, 0, stream>>>(
        src_s, t_s, dst_d, t_d, keyarr, lukey, W_ih, W_hh, b_ih, b_hh, wp8, bp);

    float* out_mem = (float*)d_out;
    float* out_lu  = out_mem + (size_t)NB * DM;
    gemm_gru_k<<<NB / BM, THREADS, 0, stream>>>(memory, last_update,
        src_s, dst_s, t_s, raw_s, src_d, dst_d, t_d, raw_d,
        w_time, b_time, wp8, bp, keyarr, lukey, out_mem, out_lu);
}

// Round 14
// 93.022 us; speedup vs baseline: 1.1785x; 1.1785x over previous
//
#include <hip/hip_runtime.h>
#include <math.h>

#define NB 65536
#define EV 131072
#define NE (2*EV)
#define DM 128
#define BM 64        // rows per gemm block
#define NT 10        // K tiles of 64
#define THREADS 512  // 8 waves, 1M x 8N, wave tile 64x64 = 2x2 MFMA 32x32

typedef float f32x4  __attribute__((ext_vector_type(4)));
typedef float f32x16 __attribute__((ext_vector_type(16)));
typedef int   i32x4  __attribute__((ext_vector_type(4)));
typedef int   i32x8  __attribute__((ext_vector_type(8)));
typedef unsigned long long u64;

// ---- fast transcendentals (HW ops) ----
__device__ __forceinline__ float fcos_rev(float rev) {
    float r; asm("v_cos_f32 %0, %1" : "=v"(r) : "v"(rev)); return r;
}
__device__ __forceinline__ float fexp2(float x) {
    float r; asm("v_exp_f32 %0, %1" : "=v"(r) : "v"(x)); return r;
}
__device__ __forceinline__ float frcp(float x) {
    float r; asm("v_rcp_f32 %0, %1" : "=v"(r) : "v"(x)); return r;
}
__device__ __forceinline__ float fast_cos(float arg) {   // |arg| up to ~1e6
    double rv = (double)arg * 0.15915494309189535;
    rv -= floor(rv);
    return fcos_rev((float)rv);
}
__device__ __forceinline__ float fsigmoid(float x) {
    x = fminf(fmaxf(x, -30.f), 30.f);
    float e = fexp2(-1.44269504088896f * x);
    return frcp(1.f + e);
}
__device__ __forceinline__ float ftanh_(float x) {
    x = fminf(fmaxf(x, -15.f), 15.f);
    float e = fexp2(-2.88539008177793f * x);
    return (1.f - e) * frcp(1.f + e);
}

// ---- fp8 e4m3 packing ----
#if defined(__has_builtin) && __has_builtin(__builtin_amdgcn_cvt_pk_fp8_f32)
__device__ __forceinline__ unsigned pack4_fp8(float f0, float f1, float f2, float f3) {
    int v = __builtin_amdgcn_cvt_pk_fp8_f32(f0, f1, 0, false);
    v = __builtin_amdgcn_cvt_pk_fp8_f32(f2, f3, v, true);
    return (unsigned)v;
}
#else
__device__ __forceinline__ unsigned enc1_fp8(float x) {
    unsigned u = __float_as_uint(x);
    unsigned s = (u >> 24) & 0x80u;
    float a = fabsf(x);
    if (!(a >= 0.001953125f)) return s;
    if (a > 448.f) a = 448.f;
    int e; float mf = frexpf(a, &e);
    int E = e + 6, mant;
    if (E <= 0) {
        mant = (int)(a * 512.f + 0.5f);
        if (mant > 7) return s | 0x08u;
        return s | (unsigned)mant;
    }
    mant = (int)((mf * 2.f - 1.f) * 8.f + 0.5f);
    if (mant == 8) { mant = 0; ++E; }
    if (E > 15) { E = 15; mant = 6; }
    if (E == 15 && mant == 7) mant = 6;
    return s | (unsigned)(E << 3) | (unsigned)mant;
}
__device__ __forceinline__ unsigned pack4_fp8(float f0, float f1, float f2, float f3) {
    return enc1_fp8(f0) | (enc1_fp8(f1) << 8) | (enc1_fp8(f2) << 16) | (enc1_fp8(f3) << 24);
}
#endif

// ---------------- event scan: argmax keys ----------------
__global__ void scan_k(const int* __restrict__ src_s, const int* __restrict__ t_s,
                       const int* __restrict__ dst_d, const int* __restrict__ t_d,
                       u64* __restrict__ keyarr, u64* __restrict__ lukey) {
    int e = blockIdx.x * 256 + threadIdx.x;
    int g, t;
    if (e < EV) { g = src_s[e];      t = t_s[e]; }
    else        { g = dst_d[e - EV]; t = t_d[e - EV]; }
    u64 key = ((u64)(unsigned)t << 18) + (u64)(unsigned)e + 1ull;
    atomicMax(&keyarr[g], key);
    u64 lk = ((u64)(unsigned)(e + 1) << 20) | (u64)(unsigned)t;   // t < 2^20
    atomicMax(&lukey[g], lk);
}

// ---------------- build: W' fp8 (blocks [0,80)) + A8 fp8 (blocks [80,1104)) ------
// Layout (both): per tile t, row/col r: 64B; 16B granule at phys pg holds
// k [t*64 + 16*(pg ^ ((r>>1)&3)), +16), values *16 for W (A unscaled).
__global__ void build_k(const u64* __restrict__ keyarr, const u64* __restrict__ lukey,
                        const float* __restrict__ memory, const int* __restrict__ last_update,
                        const int* __restrict__ src_s, const int* __restrict__ dst_s,
                        const int* __restrict__ t_s, const float* __restrict__ raw_s,
                        const int* __restrict__ src_d, const int* __restrict__ dst_d,
                        const int* __restrict__ t_d, const float* __restrict__ raw_d,
                        const float* __restrict__ w_time, const float* __restrict__ b_time,
                        const float* __restrict__ W_ih, const float* __restrict__ W_hh,
                        const float* __restrict__ b_ih, const float* __restrict__ b_hh,
                        unsigned char* __restrict__ wp8, float* __restrict__ bp,
                        unsigned char* __restrict__ a8, float* __restrict__ out_lu) {
    int bid = blockIdx.x;
    if (bid < 80) {
        // ---- W' build ----
        int idx = bid * 256 + threadIdx.x;        // [0, 20480) 16B granules
        int t = idx >> 11, r = idx & 2047;
        int c = r >> 2, pg = r & 3;
        int g = pg ^ ((c >> 1) & 3);
        int k0 = t * 64 + g * 16;
        int d = c >> 2, gate = c & 3;
        float f[16];
        #pragma unroll
        for (int j = 0; j < 16; ++j) {
            int k = k0 + j;
            float v = 0.f;
            if (k < 512) {
                int row = (gate == 0) ? d : (gate == 1) ? 128 + d : (gate == 2) ? 256 + d : -1;
                if (row >= 0) v = W_ih[(size_t)row * 512 + k];
            } else {
                int ch = k - 512;
                int row = (gate == 0) ? d : (gate == 1) ? 128 + d : (gate == 3) ? 256 + d : -1;
                if (row >= 0) v = W_hh[(size_t)row * 128 + ch];
            }
            f[j] = v * 16.f;
        }
        i32x4 v;
        v.x = (int)pack4_fp8(f[0], f[1], f[2], f[3]);
        v.y = (int)pack4_fp8(f[4], f[5], f[6], f[7]);
        v.z = (int)pack4_fp8(f[8], f[9], f[10], f[11]);
        v.w = (int)pack4_fp8(f[12], f[13], f[14], f[15]);
        *(i32x4*)(wp8 + (size_t)idx * 16) = v;
        if (k0 == 0) {
            float bv = (gate == 0) ? b_ih[d] + b_hh[d]
                     : (gate == 1) ? b_ih[128 + d] + b_hh[128 + d]
                     : (gate == 2) ? b_ih[256 + d] : b_hh[256 + d];
            bp[c] = bv;
        }
        return;
    }
    // ---- A8 build: 1024 blocks x 64 rows ----
    int blk = bid - 80;
    int m0 = blk * 64;
    int r = threadIdx.x >> 2, pg = threadIdx.x & 3;
    int m = m0 + r;
    u64 kk = keyarr[m];
    int rv = (kk != 0ull);
    int a_ = 0, b_ = 0, t_ = 0;
    const float* pR = raw_s;
    if (kk) {
        int e = (int)((kk - 1ull) & (u64)(NE - 1));
        if (e < EV) { a_ = src_s[e]; b_ = dst_s[e]; t_ = t_s[e]; pR = raw_s + (size_t)e * DM; }
        else { int e2 = e - EV; a_ = dst_d[e2]; b_ = src_d[e2]; t_ = t_d[e2]; pR = raw_d + (size_t)e2 * DM; }
    }
    const float rt = rv ? (float)(t_ - last_update[a_]) : 0.f;
    const float* pA = memory + (size_t)a_ * DM;
    const float* pB = memory + (size_t)b_ * DM;
    if (pg == 0) {
        u64 lk = lukey[m];
        out_lu[m] = lk ? (float)(unsigned)(lk & 0xFFFFFull) : (float)last_update[m];
    }
    const int g = pg ^ ((r >> 1) & 3);
    unsigned char* dst = a8 + (size_t)blk * 32768 + (size_t)threadIdx.x * 16;
    #pragma unroll
    for (int t = 0; t < 8; ++t) {
        int koff = t * 64 + g * 16;       // [0, 512)
        int seg = koff >> 7, off = koff & 127;
        float f[16];
        if (seg == 3) {
            f32x4 w0 = *(const f32x4*)(w_time + off),     w1 = *(const f32x4*)(w_time + off + 4);
            f32x4 w2 = *(const f32x4*)(w_time + off + 8), w3 = *(const f32x4*)(w_time + off + 12);
            f32x4 c0 = *(const f32x4*)(b_time + off),     c1 = *(const f32x4*)(b_time + off + 4);
            f32x4 c2 = *(const f32x4*)(b_time + off + 8), c3 = *(const f32x4*)(b_time + off + 12);
            const float* wv = (const float*)&w0; const float* cv = (const float*)&c0;
            // contiguous f32x4s: index via static unroll
            float wa[16] = {w0.x,w0.y,w0.z,w0.w,w1.x,w1.y,w1.z,w1.w,w2.x,w2.y,w2.z,w2.w,w3.x,w3.y,w3.z,w3.w};
            float ca[16] = {c0.x,c0.y,c0.z,c0.w,c1.x,c1.y,c1.z,c1.w,c2.x,c2.y,c2.z,c2.w,c3.x,c3.y,c3.z,c3.w};
            (void)wv; (void)cv;
            #pragma unroll
            for (int j = 0; j < 16; ++j)
                f[j] = fast_cos(__fadd_rn(__fmul_rn(rt, wa[j]), ca[j]));
        } else {
            const float* base = (seg == 0) ? pA : (seg == 1) ? pB : pR;
            f32x4 q0 = *(const f32x4*)(base + off);
            f32x4 q1 = *(const f32x4*)(base + off + 4);
            f32x4 q2 = *(const f32x4*)(base + off + 8);
            f32x4 q3 = *(const f32x4*)(base + off + 12);
            f[0]=q0.x; f[1]=q0.y; f[2]=q0.z; f[3]=q0.w;
            f[4]=q1.x; f[5]=q1.y; f[6]=q1.z; f[7]=q1.w;
            f[8]=q2.x; f[9]=q2.y; f[10]=q2.z; f[11]=q2.w;
            f[12]=q3.x; f[13]=q3.y; f[14]=q3.z; f[15]=q3.w;
        }
        if (!rv) {
            #pragma unroll
            for (int j = 0; j < 16; ++j) f[j] = 0.f;
        }
        i32x4 v;
        v.x = (int)pack4_fp8(f[0], f[1], f[2], f[3]);
        v.y = (int)pack4_fp8(f[4], f[5], f[6], f[7]);
        v.z = (int)pack4_fp8(f[8], f[9], f[10], f[11]);
        v.w = (int)pack4_fp8(f[12], f[13], f[14], f[15]);
        *(i32x4*)(dst + t * 4096) = v;
    }
}

// ---------------- pure MX-fp8 MFMA GEMM + GRU ----------------
__global__ __launch_bounds__(THREADS, 4) void gemm_k(
    const float* __restrict__ memory,
    const unsigned char* __restrict__ a8,
    const unsigned char* __restrict__ wp8,
    const float* __restrict__ bp,
    float* __restrict__ out_mem)
{
    // sA 2x4096 @0 | sB 2x32768 @8192  (72KB -> 2 blocks/CU)
    // epilogue: per-wave [32][68] f32 @ wn*8704 (overlay after barrier)
    __shared__ __align__(16) char smem[73728];
    unsigned char* sA = (unsigned char*)smem;
    unsigned char* sB = (unsigned char*)(smem + 8192);

    const int tid = threadIdx.x;
    const int m0  = blockIdx.x * BM;
    const int ln  = tid & 63, wn = tid >> 6;
    const int lg  = ln >> 5;

    auto STAGE_A = [&](int t, int buf) {             // 4KB, threads 0..255
        if (tid < 256) {
            const unsigned char* src = a8 + (size_t)blockIdx.x * 32768
                                          + (size_t)t * 4096 + (size_t)tid * 16;
            __builtin_amdgcn_global_load_lds(
                (const __attribute__((address_space(1))) void*)src,
                (__attribute__((address_space(3))) void*)(sA + buf * 4096 + tid * 16), 16, 0, 0);
        }
    };
    auto STAGE_B = [&](int t, int buf) {             // 32KB, 4 gll x 512 threads
        const unsigned char* src = wp8 + (size_t)t * 32768 + (size_t)tid * 16;
        unsigned char* dst = sB + (size_t)buf * 32768 + (size_t)tid * 16;
        #pragma unroll
        for (int i = 0; i < 4; ++i)
            __builtin_amdgcn_global_load_lds(
                (const __attribute__((address_space(1))) void*)(src + i * 8192),
                (__attribute__((address_space(3))) void*)(dst + i * 8192), 16, 0, 0);
    };
    auto STAGE_H = [&](int t, int buf) {             // tiles 8,9: pack h rows in-kernel
        if (tid < 256) {
            int r = tid >> 2, pg = tid & 3;
            int g = pg ^ ((r >> 1) & 3);
            const float* hp = memory + (size_t)(m0 + r) * DM + (t - 8) * 64 + g * 16;
            f32x4 q0 = *(const f32x4*)(hp);
            f32x4 q1 = *(const f32x4*)(hp + 4);
            f32x4 q2 = *(const f32x4*)(hp + 8);
            f32x4 q3 = *(const f32x4*)(hp + 12);
            i32x4 v;
            v.x = (int)pack4_fp8(q0.x, q0.y, q0.z, q0.w);
            v.y = (int)pack4_fp8(q1.x, q1.y, q1.z, q1.w);
            v.z = (int)pack4_fp8(q2.x, q2.y, q2.z, q2.w);
            v.w = (int)pack4_fp8(q3.x, q3.y, q3.z, q3.w);
            *(i32x4*)(sA + buf * 4096 + tid * 16) = v;
        }
    };

    f32x16 acc[2][2];
    #pragma unroll
    for (int mf = 0; mf < 2; ++mf)
        #pragma unroll
        for (int nf = 0; nf < 2; ++nf)
            #pragma unroll
            for (int j = 0; j < 16; ++j) acc[mf][nf][j] = 0.f;

    // prologue
    STAGE_A(0, 0);
    STAGE_B(0, 0);
    asm volatile("s_waitcnt vmcnt(0) lgkmcnt(0)" ::: "memory");
    __builtin_amdgcn_sched_barrier(0);
    __builtin_amdgcn_s_barrier();

    #pragma unroll
    for (int k = 0; k < NT; ++k) {
        const int cur = k & 1, nxt = cur ^ 1;

        // stage k+1 first (max slack before the end-of-step drain)
        if (k < NT - 1) {
            if (k + 1 < 8) STAGE_A(k + 1, nxt); else STAGE_H(k + 1, nxt);
            STAGE_B(k + 1, nxt);
        }
        __builtin_amdgcn_sched_barrier(0);

        // fragment reads (8 x b128, conflict-free granule^((r>>1)&3) swizzle)
        i32x8 af[2], bf[2];
        #pragma unroll
        for (int mf = 0; mf < 2; ++mf) {
            int r = mf * 32 + (ln & 31), sw = (r >> 1) & 3;
            i32x4 q0 = *(const i32x4*)(sA + cur * 4096 + r * 64 + (((2*lg+0) ^ sw) << 4));
            i32x4 q1 = *(const i32x4*)(sA + cur * 4096 + r * 64 + (((2*lg+1) ^ sw) << 4));
            af[mf] = (i32x8){q0.x,q0.y,q0.z,q0.w, q1.x,q1.y,q1.z,q1.w};
        }
        #pragma unroll
        for (int nf = 0; nf < 2; ++nf) {
            int c = wn * 64 + nf * 32 + (ln & 31), sw = (c >> 1) & 3;
            i32x4 q0 = *(const i32x4*)(sB + cur * 32768 + c * 64 + (((2*lg+0) ^ sw) << 4));
            i32x4 q1 = *(const i32x4*)(sB + cur * 32768 + c * 64 + (((2*lg+1) ^ sw) << 4));
            bf[nf] = (i32x8){q0.x,q0.y,q0.z,q0.w, q1.x,q1.y,q1.z,q1.w};
        }
        asm volatile("s_waitcnt lgkmcnt(0)" ::: "memory");
        __builtin_amdgcn_sched_barrier(0);

        __builtin_amdgcn_s_setprio(1);
        #pragma unroll
        for (int mf = 0; mf < 2; ++mf)
            #pragma unroll
            for (int nf = 0; nf < 2; ++nf)
                acc[mf][nf] = __builtin_amdgcn_mfma_scale_f32_32x32x64_f8f6f4(
                    af[mf], bf[nf], acc[mf][nf], 0, 0, 0, 127, 0, 127);
        __builtin_amdgcn_s_setprio(0);

        if (k < NT - 1) {
            __builtin_amdgcn_sched_barrier(0);
            asm volatile("s_waitcnt vmcnt(0) lgkmcnt(0)" ::: "memory");
            __builtin_amdgcn_sched_barrier(0);
            __builtin_amdgcn_s_barrier();
        }
    }

    __syncthreads();    // all LDS frag reads done; per-wave scratch overlays sA/sB

    // ---- epilogue: per-wave LDS transpose (32x32 C layout), fused GRU ----
    float* ep = (float*)(smem + wn * 8704);           // [32][68] f32
    const int erow = ln >> 1, half = ln & 1;
    const int d0 = wn * 16 + half * 8;                // 8 d-channels per lane
    const float ds = 0.0625f;                          // 1/16 (W scale)

    #pragma unroll
    for (int mf = 0; mf < 2; ++mf) {
        #pragma unroll
        for (int nf = 0; nf < 2; ++nf)
            #pragma unroll
            for (int reg = 0; reg < 16; ++reg) {
                int r32 = (reg & 3) + 8 * (reg >> 2) + 4 * lg;   // 0..31
                ep[r32 * 68 + nf * 32 + (ln & 31)] = acc[mf][nf][reg] * ds;
            }
        asm volatile("s_waitcnt lgkmcnt(0)" ::: "memory");

        const int gm = m0 + mf * 32 + erow;
        const float* gr = ep + erow * 68 + half * 32;
        float res[8];
        f32x4 h0 = *(const f32x4*)(memory + (size_t)gm * DM + d0);
        f32x4 h1 = *(const f32x4*)(memory + (size_t)gm * DM + d0 + 4);
        #pragma unroll
        for (int q = 0; q < 8; ++q) {
            f32x4 g  = *(const f32x4*)(gr + q * 4);
            f32x4 bb = *(const f32x4*)(bp + (d0 + q) * 4);
            float rg = fsigmoid(g.x + bb.x);
            float zg = fsigmoid(g.y + bb.y);
            float ng = ftanh_(g.z + bb.z + rg * (g.w + bb.w));
            float hh = (q < 4) ? ((const float*)&h0)[q] : ((const float*)&h1)[q - 4];
            res[q] = (1.f - zg) * ng + zg * hh;
        }
        *(f32x4*)(out_mem + (size_t)gm * DM + d0)     = *(const f32x4*)res;
        *(f32x4*)(out_mem + (size_t)gm * DM + d0 + 4) = *(const f32x4*)(res + 4);
        if (mf == 0) asm volatile("s_waitcnt lgkmcnt(0)" ::: "memory");
    }
}

extern "C" void kernel_launch(void* const* d_in, const int* in_sizes, int n_in,
                              void* d_out, int out_size, void* d_ws, size_t ws_size,
                              hipStream_t stream) {
    const float* memory      = (const float*)d_in[0];
    const int*   last_update = (const int*)d_in[1];
    const int*   src_s       = (const int*)d_in[3];
    const int*   dst_s       = (const int*)d_in[4];
    const int*   t_s         = (const int*)d_in[5];
    const float* raw_s       = (const float*)d_in[6];
    const int*   src_d       = (const int*)d_in[7];
    const int*   dst_d       = (const int*)d_in[8];
    const int*   t_d         = (const int*)d_in[9];
    const float* raw_d       = (const float*)d_in[10];
    const float* w_time      = (const float*)d_in[11];
    const float* b_time      = (const float*)d_in[12];
    const float* W_ih        = (const float*)d_in[13];
    const float* W_hh        = (const float*)d_in[14];
    const float* b_ih        = (const float*)d_in[15];
    const float* b_hh        = (const float*)d_in[16];

    // workspace
    char* ws = (char*)d_ws;
    u64* keyarr = (u64*)ws;                                 // 512KB
    u64* lukey  = (u64*)(ws + 524288);                      // 512KB
    unsigned char* wp8 = (unsigned char*)(ws + 1048576);    // 320KB (10 tiles x 32KB)
    float* bp = (float*)(ws + 1376256);                     // 2KB

    float* out_mem = (float*)d_out;
    float* out_lu  = out_mem + (size_t)NB * DM;
    unsigned char* a8 = (unsigned char*)d_out;              // A8 aliases out_mem (33.55MB)

    hipMemsetAsync(d_ws, 0, 1048576, stream);               // keyarr + lukey

    scan_k<<<NE / 256, 256, 0, stream>>>(src_s, t_s, dst_d, t_d, keyarr, lukey);
    build_k<<<80 + NB / 64, 256, 0, stream>>>(keyarr, lukey, memory, last_update,
        src_s, dst_s, t_s, raw_s, src_d, dst_d, t_d, raw_d,
        w_time, b_time, W_ih, W_hh, b_ih, b_hh, wp8, bp, a8, out_lu);
    gemm_k<<<NB / BM, THREADS, 0, stream>>>(memory, a8, wp8, bp, out_mem);
}